// Round 1
// baseline (2785.123 us; speedup 1.0000x reference)
//
#include <hip/hip_runtime.h>
#include <cstdint>

#define B_ 4
#define S_ 2048
#define D_ 512
#define H_ 8
#define DK_ 64
#define SCALE 0.125f

__device__ __forceinline__ float readlane_f(float v, int lane) {
  return __builtin_bit_cast(float, __builtin_amdgcn_readlane(__builtin_bit_cast(int, v), lane));
}

// ---------------------------------------------------------------------------
// C[M,N] = A[M,512] @ W[:, colOff:colOff+512]   (M=8192, Kdim=512, N=512)
// BM=BN=64, BK=16, 256 threads, 4x4 micro-tile, fp32.
// headsplit=1: store as [B,H,S,DK]; headsplit=0: store as [M,512] flat.
// ---------------------------------------------------------------------------
__global__ __launch_bounds__(256) void gemm_proj(
    const float* __restrict__ A, const float* __restrict__ W, int ldw, int colOff,
    float* __restrict__ out, int headsplit)
{
  __shared__ float As[16][68];   // [k][m] (transposed at store)
  __shared__ float Bs[16][68];   // [k][n]
  const int tid = threadIdx.x;
  const int m0 = blockIdx.y * 64;
  const int n0 = blockIdx.x * 64;
  const int tx = tid & 15, ty = tid >> 4;

  float acc[4][4];
#pragma unroll
  for (int i = 0; i < 4; i++)
#pragma unroll
    for (int j = 0; j < 4; j++) acc[i][j] = 0.f;

  const int ar = tid >> 2, ac = (tid & 3) * 4;   // A stage: row ar, k-cols ac..ac+3
  const int br = tid >> 4, bc = (tid & 15) * 4;  // B stage: k-row br, n-cols bc..bc+3

  for (int kt = 0; kt < 512; kt += 16) {
    float4 av = *(const float4*)&A[(size_t)(m0 + ar) * 512 + kt + ac];
    float4 bv = *(const float4*)&W[(size_t)(kt + br) * ldw + colOff + n0 + bc];
    __syncthreads();
    As[ac + 0][ar] = av.x; As[ac + 1][ar] = av.y;
    As[ac + 2][ar] = av.z; As[ac + 3][ar] = av.w;
    *(float4*)&Bs[br][bc] = bv;
    __syncthreads();
#pragma unroll
    for (int k = 0; k < 16; k++) {
      float4 a4 = *(float4*)&As[k][ty * 4];
      float4 b4 = *(float4*)&Bs[k][tx * 4];
      acc[0][0] = fmaf(a4.x, b4.x, acc[0][0]);
      acc[0][1] = fmaf(a4.x, b4.y, acc[0][1]);
      acc[0][2] = fmaf(a4.x, b4.z, acc[0][2]);
      acc[0][3] = fmaf(a4.x, b4.w, acc[0][3]);
      acc[1][0] = fmaf(a4.y, b4.x, acc[1][0]);
      acc[1][1] = fmaf(a4.y, b4.y, acc[1][1]);
      acc[1][2] = fmaf(a4.y, b4.z, acc[1][2]);
      acc[1][3] = fmaf(a4.y, b4.w, acc[1][3]);
      acc[2][0] = fmaf(a4.z, b4.x, acc[2][0]);
      acc[2][1] = fmaf(a4.z, b4.y, acc[2][1]);
      acc[2][2] = fmaf(a4.z, b4.z, acc[2][2]);
      acc[2][3] = fmaf(a4.z, b4.w, acc[2][3]);
      acc[3][0] = fmaf(a4.w, b4.x, acc[3][0]);
      acc[3][1] = fmaf(a4.w, b4.y, acc[3][1]);
      acc[3][2] = fmaf(a4.w, b4.z, acc[3][2]);
      acc[3][3] = fmaf(a4.w, b4.w, acc[3][3]);
    }
  }

#pragma unroll
  for (int i = 0; i < 4; i++) {
    const int m = m0 + ty * 4 + i;
    float4 v; v.x = acc[i][0]; v.y = acc[i][1]; v.z = acc[i][2]; v.w = acc[i][3];
    if (headsplit) {
      const int bb = m >> 11;            // m / S_
      const int s  = m & (S_ - 1);
      const int h  = n0 >> 6;            // block spans exactly one head
      const size_t base = (((size_t)bb * H_ + h) * S_ + s) * DK_;
      *(float4*)&out[base + tx * 4] = v;
    } else {
      *(float4*)&out[(size_t)m * 512 + n0 + tx * 4] = v;
    }
  }
}

// ---------------------------------------------------------------------------
// Pass 1: per-(b,h,q) row-max m and row-sum l of exp(logit - m).
// One wave per block, 8 q-rows, lanes = k within a 64-wide K tile.
// ---------------------------------------------------------------------------
__global__ __launch_bounds__(64) void attn_stats(
    const float* __restrict__ Qws, const float* __restrict__ Kws,
    const float* __restrict__ mask, float* __restrict__ mrow, float* __restrict__ lrow)
{
  __shared__ float Ks[64][68];
  const int lane = threadIdx.x;
  const int blk  = blockIdx.x;
  const int qt   = blk & 255;       // S_/8 = 256 q-tiles
  const int bh   = blk >> 8;        // 0..31
  const int q0   = qt * 8;
  const float* Kbase = Kws + (size_t)bh * S_ * DK_;
  const float* Qbase = Qws + ((size_t)bh * S_ + q0) * DK_;

  float m[8], l[8];
#pragma unroll
  for (int q = 0; q < 8; q++) { m[q] = -3.0e38f; l[q] = 0.f; }

  for (int kt = 0; kt < S_; kt += 64) {
    __syncthreads();
#pragma unroll
    for (int i = 0; i < 16; i++) {
      const int f = lane + 64 * i;
      const int r = f >> 4, c = (f & 15) * 4;
      *(float4*)&Ks[r][c] = *(const float4*)&Kbase[(size_t)(kt + r) * DK_ + c];
    }
    __syncthreads();

    float z[8];
#pragma unroll
    for (int q = 0; q < 8; q++) z[q] = 0.f;
#pragma unroll 4
    for (int dc = 0; dc < 64; dc += 4) {
      float4 kv = *(float4*)&Ks[lane][dc];
#pragma unroll
      for (int q = 0; q < 8; q++) {
        float4 qv = *(const float4*)&Qbase[q * DK_ + dc];  // block-uniform address
        z[q] = fmaf(qv.x, kv.x, z[q]);
        z[q] = fmaf(qv.y, kv.y, z[q]);
        z[q] = fmaf(qv.z, kv.z, z[q]);
        z[q] = fmaf(qv.w, kv.w, z[q]);
      }
    }
    const int kg = kt + lane;
#pragma unroll
    for (int q = 0; q < 8; q++) {
      const float zf = fmaf(z[q], SCALE, mask[(size_t)(q0 + q) * S_ + kg]);
      const float nm = fmaxf(m[q], zf);
      l[q] = l[q] * __expf(m[q] - nm) + __expf(zf - nm);
      m[q] = nm;
    }
  }

  // wave-wide (m,l) combine
#pragma unroll
  for (int q = 0; q < 8; q++) {
#pragma unroll
    for (int off = 32; off > 0; off >>= 1) {
      const float om = __shfl_xor(m[q], off, 64);
      const float ol = __shfl_xor(l[q], off, 64);
      const float nm = fmaxf(m[q], om);
      l[q] = l[q] * __expf(m[q] - nm) + ol * __expf(om - nm);
      m[q] = nm;
    }
  }
  if (lane == 0) {
#pragma unroll
    for (int q = 0; q < 8; q++) {
      mrow[(size_t)bh * S_ + q0 + q] = m[q];
      lrow[(size_t)bh * S_ + q0 + q] = l[q];
    }
  }
}

// ---------------------------------------------------------------------------
// Pass 2: per (b, 32-row tile): loop all 8 heads; recompute logits per K-tile,
// p = exp(z-m)/l; accumulate head-mean in registers (written once, no atomics);
// accumulate ctx[q][h] with lanes = dk, p delivered via v_readlane (SGPR
// operand to fmac — avoids LDS-broadcast-per-MAC).
// ---------------------------------------------------------------------------
__global__ __launch_bounds__(512) void attn_ctx(
    const float* __restrict__ Qws, const float* __restrict__ Kws, const float* __restrict__ Vws,
    const float* __restrict__ mask, const float* __restrict__ mrow, const float* __restrict__ lrow,
    float* __restrict__ ctxws, float* __restrict__ meanout)
{
  __shared__ float Ks[64][68];
  __shared__ float Vs[64][68];
  const int tid  = threadIdx.x;
  const int wv   = tid >> 6;
  const int lane = tid & 63;
  const int b    = blockIdx.y;
  const int q0   = blockIdx.x * 32;
  const int qr   = q0 + wv * 4;       // this wave's first q-row

  float ctx[4][8];
#pragma unroll
  for (int q = 0; q < 4; q++)
#pragma unroll
    for (int h = 0; h < 8; h++) ctx[q][h] = 0.f;

  for (int kt = 0; kt < S_; kt += 64) {
    float macc[4] = {0.f, 0.f, 0.f, 0.f};
#pragma unroll
    for (int h = 0; h < H_; h++) {
      const size_t bh = (size_t)b * H_ + h;
      const float* Kb = Kws + (bh * S_ + kt) * DK_;
      const float* Vb = Vws + (bh * S_ + kt) * DK_;
      __syncthreads();
#pragma unroll
      for (int i = 0; i < 2; i++) {
        const int f = tid + 512 * i;
        const int r = f >> 4, c = (f & 15) * 4;
        *(float4*)&Ks[r][c] = *(const float4*)&Kb[(size_t)r * DK_ + c];
        *(float4*)&Vs[r][c] = *(const float4*)&Vb[(size_t)r * DK_ + c];
      }
      __syncthreads();

      const float* Qb = Qws + (bh * S_ + qr) * DK_;
      float z[4] = {0.f, 0.f, 0.f, 0.f};
#pragma unroll 4
      for (int dc = 0; dc < 64; dc += 4) {
        float4 kv = *(float4*)&Ks[lane][dc];
#pragma unroll
        for (int q = 0; q < 4; q++) {
          float4 qv = *(const float4*)&Qb[q * DK_ + dc];
          z[q] = fmaf(qv.x, kv.x, z[q]);
          z[q] = fmaf(qv.y, kv.y, z[q]);
          z[q] = fmaf(qv.z, kv.z, z[q]);
          z[q] = fmaf(qv.w, kv.w, z[q]);
        }
      }
      const int kg = kt + lane;
#pragma unroll
      for (int q = 0; q < 4; q++) {
        const float mm = mrow[bh * S_ + qr + q];
        const float ll = lrow[bh * S_ + qr + q];
        const float zf = fmaf(z[q], SCALE, mask[(size_t)(qr + q) * S_ + kg]);
        const float p  = __expf(zf - mm) * (1.0f / ll);
        macc[q] += p * 0.125f;       // mean over H heads
        z[q] = p;                     // z now holds p (lane = k)
      }
      // ctx accumulation: lanes = dk
      for (int kk = 0; kk < 64; kk += 4) {
        const float v0 = Vs[kk + 0][lane];
        const float v1 = Vs[kk + 1][lane];
        const float v2 = Vs[kk + 2][lane];
        const float v3 = Vs[kk + 3][lane];
#pragma unroll
        for (int q = 0; q < 4; q++) {
          const float p0 = readlane_f(z[q], kk + 0);
          const float p1 = readlane_f(z[q], kk + 1);
          const float p2 = readlane_f(z[q], kk + 2);
          const float p3 = readlane_f(z[q], kk + 3);
          float c = ctx[q][h];
          c = fmaf(p0, v0, c);
          c = fmaf(p1, v1, c);
          c = fmaf(p2, v2, c);
          c = fmaf(p3, v3, c);
          ctx[q][h] = c;
        }
      }
    }
#pragma unroll
    for (int q = 0; q < 4; q++)
      meanout[((size_t)b * S_ + qr + q) * S_ + kt + lane] = macc[q];
  }

#pragma unroll
  for (int q = 0; q < 4; q++)
#pragma unroll
    for (int h = 0; h < 8; h++)
      ctxws[((size_t)b * S_ + qr + q) * D_ + h * DK_ + lane] = ctx[q][h];
}

// ---------------------------------------------------------------------------
extern "C" void kernel_launch(void* const* d_in, const int* in_sizes, int n_in,
                              void* d_out, int out_size, void* d_ws, size_t ws_size,
                              hipStream_t stream) {
  (void)in_sizes; (void)n_in; (void)out_size; (void)ws_size;
  const float* Zq   = (const float*)d_in[0];
  const float* Zkv  = (const float*)d_in[1];
  const float* mask = (const float*)d_in[2];
  const float* Wqkv = (const float*)d_in[3];
  const float* Wout = (const float*)d_in[4];

  float* out  = (float*)d_out;                       // [B,S,D]
  float* mean = out + (size_t)B_ * S_ * D_;          // [B,S,S]

  float* ws  = (float*)d_ws;
  float* Q   = ws;                  // [B,H,S,DK]  4194304 floats
  float* K   = ws + 4194304;        // [B,H,S,DK]
  float* V   = ws + 8388608;        // [B,H,S,DK]
  float* CTX = ws + 12582912;       // [B,S,D]
  float* MR  = ws + 16777216;       // [B,H,S]
  float* LR  = ws + 16842752;       // [B,H,S]

  dim3 gp(8, 128);   // N/64 x M/64
  gemm_proj<<<gp, 256, 0, stream>>>(Zq,  Wqkv, 1536, 0,    Q, 1);
  gemm_proj<<<gp, 256, 0, stream>>>(Zkv, Wqkv, 1536, 512,  K, 1);
  gemm_proj<<<gp, 256, 0, stream>>>(Zkv, Wqkv, 1536, 1024, V, 1);
  attn_stats<<<8192, 64, 0, stream>>>(Q, K, mask, MR, LR);
  attn_ctx<<<dim3(64, 4), 512, 0, stream>>>(Q, K, V, mask, MR, LR, CTX, mean);
  gemm_proj<<<gp, 256, 0, stream>>>(CTX, Wout, 512, 0, out, 0);
}

// Round 2
// 536.798 us; speedup vs baseline: 5.1884x; 5.1884x over previous
//
#include <hip/hip_runtime.h>
#include <cstdint>

#define B_ 4
#define S_ 2048
#define D_ 512
#define H_ 8
#define DK_ 64
#define SCALE 0.125f

using bfrag = __attribute__((ext_vector_type(8))) __bf16;
using f4    = __attribute__((ext_vector_type(4))) float;

#define MFMA16(a, b, c) __builtin_amdgcn_mfma_f32_16x16x32_bf16(a, b, c, 0, 0, 0)

// ---------------------------------------------------------------------------
// Weight transpose + split: WT[n][k] = W[k][c0+n], hi/lo bf16.
// ---------------------------------------------------------------------------
__global__ __launch_bounds__(256) void wtr(const float* __restrict__ W, int ldw, int c0,
                                           __bf16* __restrict__ th, __bf16* __restrict__ tl,
                                           int do_lo) {
  int idx = blockIdx.x * 256 + threadIdx.x;  // 512*512
  int k = idx & 511, n = idx >> 9;
  float x = W[(size_t)k * ldw + c0 + n];
  __bf16 h = (__bf16)x;
  th[(size_t)n * 512 + k] = h;
  if (do_lo) tl[(size_t)n * 512 + k] = (__bf16)(x - (float)h);
}

// ---------------------------------------------------------------------------
// Split-bf16 MFMA GEMM. C[M x N] = A[M x 512] * B[512 x N], K=512 fixed.
// A source: fp32 [m][k] (split at staging) or bf16-hi [m][k].
// B source: pre-split bf16 W^T-layout [n][k], or fp32 [n][k] (hi at staging).
// MODE 0: fp32 C[m*512+n].  MODE 1: head-split hi/lo bf16 [B,H,S,DK] (N=512).
// MODE 2: bf16 V^T [B,H,DK,S] (m=d-dim, n=b*S+s).
// 64x64 tile, BK=32, 4 waves of 2x2 MFMA subtiles.
// ---------------------------------------------------------------------------
template <bool AF32, bool BF32, bool LO, int MODE>
__global__ __launch_bounds__(256) void gemm_mfma(
    const void* __restrict__ Ap, const void* __restrict__ Bp, const void* __restrict__ Blop,
    float* __restrict__ Cf, __bf16* __restrict__ Oh, __bf16* __restrict__ Ol) {
  __shared__ __bf16 Ash[64 * 40];
  __shared__ __bf16 Asl[64 * 40];
  __shared__ __bf16 Bsh[64 * 40];
  __shared__ __bf16 Bsl[64 * 40];

  const int tid = threadIdx.x;
  const int m0 = blockIdx.y * 64, n0 = blockIdx.x * 64;
  const int row = tid >> 2, seg = tid & 3;  // stage: 8 k-elems per thread
  const int lane = tid & 63, wv = tid >> 6;
  const int wm = (wv & 1) * 32, wn = (wv >> 1) * 32;
  const int qd = lane >> 4, ln = lane & 15;

  f4 acc[2][2];
#pragma unroll
  for (int i = 0; i < 2; i++)
#pragma unroll
    for (int j = 0; j < 2; j++)
#pragma unroll
      for (int r = 0; r < 4; r++) acc[i][j][r] = 0.f;

  for (int kt = 0; kt < 512; kt += 32) {
    const size_t abase = (size_t)(m0 + row) * 512 + kt + seg * 8;
    const size_t bbase = (size_t)(n0 + row) * 512 + kt + seg * 8;
    float4 a0, a1, b0, b1, bl0;
    if constexpr (AF32) {
      const float* A = (const float*)Ap;
      a0 = *(const float4*)&A[abase];
      a1 = *(const float4*)&A[abase + 4];
    } else {
      const __bf16* A = (const __bf16*)Ap;
      a0 = *(const float4*)&A[abase];
    }
    if constexpr (BF32) {
      const float* Bm = (const float*)Bp;
      b0 = *(const float4*)&Bm[bbase];
      b1 = *(const float4*)&Bm[bbase + 4];
    } else {
      const __bf16* Bm = (const __bf16*)Bp;
      b0 = *(const float4*)&Bm[bbase];
      if constexpr (LO) {
        const __bf16* Bl = (const __bf16*)Blop;
        bl0 = *(const float4*)&Bl[bbase];
      }
    }
    __syncthreads();
    if constexpr (AF32) {
      float x[8] = {a0.x, a0.y, a0.z, a0.w, a1.x, a1.y, a1.z, a1.w};
      bfrag h, l;
#pragma unroll
      for (int j = 0; j < 8; j++) {
        h[j] = (__bf16)x[j];
        l[j] = (__bf16)(x[j] - (float)h[j]);
      }
      *(bfrag*)&Ash[row * 40 + seg * 8] = h;
      if constexpr (LO) *(bfrag*)&Asl[row * 40 + seg * 8] = l;
    } else {
      *(float4*)&Ash[row * 40 + seg * 8] = a0;
    }
    if constexpr (BF32) {
      float x[8] = {b0.x, b0.y, b0.z, b0.w, b1.x, b1.y, b1.z, b1.w};
      bfrag h;
#pragma unroll
      for (int j = 0; j < 8; j++) h[j] = (__bf16)x[j];
      *(bfrag*)&Bsh[row * 40 + seg * 8] = h;
    } else {
      *(float4*)&Bsh[row * 40 + seg * 8] = b0;
      if constexpr (LO) *(float4*)&Bsl[row * 40 + seg * 8] = bl0;
    }
    __syncthreads();

    bfrag ah[2], al[2], bh[2], bl[2];
#pragma unroll
    for (int mi = 0; mi < 2; mi++) {
      ah[mi] = *(bfrag*)&Ash[(wm + mi * 16 + ln) * 40 + qd * 8];
      if constexpr (LO) al[mi] = *(bfrag*)&Asl[(wm + mi * 16 + ln) * 40 + qd * 8];
    }
#pragma unroll
    for (int ni = 0; ni < 2; ni++) {
      bh[ni] = *(bfrag*)&Bsh[(wn + ni * 16 + ln) * 40 + qd * 8];
      if constexpr (LO) bl[ni] = *(bfrag*)&Bsl[(wn + ni * 16 + ln) * 40 + qd * 8];
    }
#pragma unroll
    for (int mi = 0; mi < 2; mi++)
#pragma unroll
      for (int ni = 0; ni < 2; ni++) {
        acc[mi][ni] = MFMA16(ah[mi], bh[ni], acc[mi][ni]);
        if constexpr (LO) {
          acc[mi][ni] = MFMA16(ah[mi], bl[ni], acc[mi][ni]);
          acc[mi][ni] = MFMA16(al[mi], bh[ni], acc[mi][ni]);
        }
      }
  }

#pragma unroll
  for (int mi = 0; mi < 2; mi++)
#pragma unroll
    for (int ni = 0; ni < 2; ni++)
#pragma unroll
      for (int r = 0; r < 4; r++) {
        const int mrow = m0 + wm + mi * 16 + qd * 4 + r;
        const int ncol = n0 + wn + ni * 16 + ln;
        const float c = acc[mi][ni][r];
        if constexpr (MODE == 0) {
          Cf[(size_t)mrow * 512 + ncol] = c;
        } else if constexpr (MODE == 1) {
          const int b = mrow >> 11, s = mrow & (S_ - 1);
          const int h = ncol >> 6, dk = ncol & 63;
          const size_t o = (((size_t)b * H_ + h) * S_ + s) * DK_ + dk;
          __bf16 hh = (__bf16)c;
          Oh[o] = hh;
          Ol[o] = (__bf16)(c - (float)hh);
        } else {  // MODE 2: V^T
          const int h = mrow >> 6, dk = mrow & 63;
          const int b = ncol >> 11, s = ncol & (S_ - 1);
          Oh[(((size_t)b * H_ + h) * DK_ + dk) * S_ + s] = (__bf16)c;
        }
      }
}

// ---------------------------------------------------------------------------
// Pass 1: online (m,l) per row via MFMA QK^T. Block 256 = 4 waves x 16 q-rows.
// ---------------------------------------------------------------------------
__global__ __launch_bounds__(256) void attn_stats(
    const __bf16* __restrict__ Qh, const __bf16* __restrict__ Ql,
    const __bf16* __restrict__ Kh, const __bf16* __restrict__ Kl,
    const float* __restrict__ mask, float* __restrict__ mrow, float* __restrict__ lrow) {
  __shared__ __bf16 Ksh[64 * 72];
  __shared__ __bf16 Ksl[64 * 72];
  const int tid = threadIdx.x, lane = tid & 63, wv = tid >> 6;
  const int qd = lane >> 4, ln = lane & 15;
  const int qt = blockIdx.x, bh = blockIdx.y;
  const int q0w = qt * 64 + wv * 16;
  const int srow = tid >> 2, sseg = tid & 3;

  const size_t qbase = ((size_t)bh * S_ + q0w + ln) * DK_;
  bfrag qh[2], ql[2];
#pragma unroll
  for (int s = 0; s < 2; s++) {
    qh[s] = *(const bfrag*)&Qh[qbase + s * 32 + qd * 8];
    ql[s] = *(const bfrag*)&Ql[qbase + s * 32 + qd * 8];
  }

  float m[4], l[4];
#pragma unroll
  for (int r = 0; r < 4; r++) { m[r] = -3.0e38f; l[r] = 0.f; }

  for (int kt = 0; kt < S_; kt += 64) {
    const size_t kb = ((size_t)bh * S_ + kt + srow) * DK_ + sseg * 16;
    float4 h0 = *(const float4*)&Kh[kb], h1 = *(const float4*)&Kh[kb + 8];
    float4 l0 = *(const float4*)&Kl[kb], l1 = *(const float4*)&Kl[kb + 8];
    __syncthreads();
    *(float4*)&Ksh[srow * 72 + sseg * 16] = h0;
    *(float4*)&Ksh[srow * 72 + sseg * 16 + 8] = h1;
    *(float4*)&Ksl[srow * 72 + sseg * 16] = l0;
    *(float4*)&Ksl[srow * 72 + sseg * 16 + 8] = l1;
    __syncthreads();

    f4 z[4];
#pragma unroll
    for (int t = 0; t < 4; t++) {
#pragma unroll
      for (int r = 0; r < 4; r++) z[t][r] = 0.f;
#pragma unroll
      for (int s = 0; s < 2; s++) {
        bfrag kbh = *(bfrag*)&Ksh[(t * 16 + ln) * 72 + s * 32 + qd * 8];
        bfrag kbl = *(bfrag*)&Ksl[(t * 16 + ln) * 72 + s * 32 + qd * 8];
        z[t] = MFMA16(qh[s], kbh, z[t]);
        z[t] = MFMA16(qh[s], kbl, z[t]);
        z[t] = MFMA16(ql[s], kbh, z[t]);
      }
    }

    float zf[4][4];
#pragma unroll
    for (int t = 0; t < 4; t++)
#pragma unroll
      for (int r = 0; r < 4; r++)
        zf[t][r] = fmaf(z[t][r], SCALE,
                        mask[(size_t)(q0w + qd * 4 + r) * S_ + kt + t * 16 + ln]);
#pragma unroll
    for (int r = 0; r < 4; r++) {
      float cm = fmaxf(fmaxf(zf[0][r], zf[1][r]), fmaxf(zf[2][r], zf[3][r]));
#pragma unroll
      for (int off = 1; off < 16; off <<= 1) cm = fmaxf(cm, __shfl_xor(cm, off, 64));
      const float nm = fmaxf(m[r], cm);
      float ps = __expf(zf[0][r] - nm) + __expf(zf[1][r] - nm) +
                 __expf(zf[2][r] - nm) + __expf(zf[3][r] - nm);
#pragma unroll
      for (int off = 1; off < 16; off <<= 1) ps += __shfl_xor(ps, off, 64);
      l[r] = l[r] * __expf(m[r] - nm) + ps;
      m[r] = nm;
    }
  }
  if (ln == 0) {
#pragma unroll
    for (int r = 0; r < 4; r++) {
      mrow[(size_t)bh * S_ + q0w + qd * 4 + r] = m[r];
      lrow[(size_t)bh * S_ + q0w + qd * 4 + r] = l[r];
    }
  }
}

// ---------------------------------------------------------------------------
// Pass 2a: ctx = softmax(QK^T) V via MFMA; P transposed through LDS (m120).
// ---------------------------------------------------------------------------
__global__ __launch_bounds__(256) void attn_ctx(
    const __bf16* __restrict__ Qh, const __bf16* __restrict__ Ql,
    const __bf16* __restrict__ Kh, const __bf16* __restrict__ Kl,
    const __bf16* __restrict__ VT, const float* __restrict__ mask,
    const float* __restrict__ mrow, const float* __restrict__ lrow,
    __bf16* __restrict__ CTXb) {
  __shared__ __bf16 Ksh[64 * 72];
  __shared__ __bf16 Ksl[64 * 72];
  __shared__ __bf16 Vs[64 * 72];
  __shared__ __bf16 Ps[4 * 16 * 72];
  const int tid = threadIdx.x, lane = tid & 63, wv = tid >> 6;
  const int qd = lane >> 4, ln = lane & 15;
  const int qt = blockIdx.x, bh = blockIdx.y;
  const int q0w = qt * 64 + wv * 16;
  const int srow = tid >> 2, sseg = tid & 3;

  const size_t qbase = ((size_t)bh * S_ + q0w + ln) * DK_;
  bfrag qh[2], ql[2];
#pragma unroll
  for (int s = 0; s < 2; s++) {
    qh[s] = *(const bfrag*)&Qh[qbase + s * 32 + qd * 8];
    ql[s] = *(const bfrag*)&Ql[qbase + s * 32 + qd * 8];
  }
  float m[4], invl[4];
#pragma unroll
  for (int r = 0; r < 4; r++) {
    m[r] = mrow[(size_t)bh * S_ + q0w + qd * 4 + r];
    invl[r] = 1.0f / lrow[(size_t)bh * S_ + q0w + qd * 4 + r];
  }

  f4 cacc[4];
#pragma unroll
  for (int t = 0; t < 4; t++)
#pragma unroll
    for (int r = 0; r < 4; r++) cacc[t][r] = 0.f;

  for (int kt = 0; kt < S_; kt += 64) {
    const size_t kb = ((size_t)bh * S_ + kt + srow) * DK_ + sseg * 16;
    const size_t vb = ((size_t)bh * DK_ + srow) * S_ + kt + sseg * 16;
    float4 h0 = *(const float4*)&Kh[kb], h1 = *(const float4*)&Kh[kb + 8];
    float4 l0 = *(const float4*)&Kl[kb], l1 = *(const float4*)&Kl[kb + 8];
    float4 v0 = *(const float4*)&VT[vb], v1 = *(const float4*)&VT[vb + 8];
    __syncthreads();
    *(float4*)&Ksh[srow * 72 + sseg * 16] = h0;
    *(float4*)&Ksh[srow * 72 + sseg * 16 + 8] = h1;
    *(float4*)&Ksl[srow * 72 + sseg * 16] = l0;
    *(float4*)&Ksl[srow * 72 + sseg * 16 + 8] = l1;
    *(float4*)&Vs[srow * 72 + sseg * 16] = v0;
    *(float4*)&Vs[srow * 72 + sseg * 16 + 8] = v1;
    __syncthreads();

    f4 z[4];
#pragma unroll
    for (int t = 0; t < 4; t++) {
#pragma unroll
      for (int r = 0; r < 4; r++) z[t][r] = 0.f;
#pragma unroll
      for (int s = 0; s < 2; s++) {
        bfrag kbh = *(bfrag*)&Ksh[(t * 16 + ln) * 72 + s * 32 + qd * 8];
        bfrag kbl = *(bfrag*)&Ksl[(t * 16 + ln) * 72 + s * 32 + qd * 8];
        z[t] = MFMA16(qh[s], kbh, z[t]);
        z[t] = MFMA16(qh[s], kbl, z[t]);
        z[t] = MFMA16(ql[s], kbh, z[t]);
      }
    }
#pragma unroll
    for (int t = 0; t < 4; t++)
#pragma unroll
      for (int r = 0; r < 4; r++) {
        const float zf = fmaf(z[t][r], SCALE,
                              mask[(size_t)(q0w + qd * 4 + r) * S_ + kt + t * 16 + ln]);
        const float p = __expf(zf - m[r]) * invl[r];
        Ps[(wv * 16 + qd * 4 + r) * 72 + t * 16 + ln] = (__bf16)p;
      }
    bfrag pa[2];
#pragma unroll
    for (int s = 0; s < 2; s++)
      pa[s] = *(bfrag*)&Ps[(wv * 16 + ln) * 72 + s * 32 + qd * 8];
#pragma unroll
    for (int t = 0; t < 4; t++)
#pragma unroll
      for (int s = 0; s < 2; s++) {
        bfrag vbf = *(bfrag*)&Vs[(t * 16 + ln) * 72 + s * 32 + qd * 8];
        cacc[t] = MFMA16(pa[s], vbf, cacc[t]);
      }
  }

  const int b = bh >> 3, h = bh & 7;
#pragma unroll
  for (int t = 0; t < 4; t++)
#pragma unroll
    for (int r = 0; r < 4; r++) {
      const int s = q0w + qd * 4 + r;
      CTXb[((size_t)b * S_ + s) * D_ + h * DK_ + t * 16 + ln] = (__bf16)cacc[t][r];
    }
}

// ---------------------------------------------------------------------------
// Pass 2b: mean over heads of P, accumulated in registers, written once.
// Grid (qt, kv-slice, b); loops h. kv-slice = 256 kv (4 tiles of 64).
// ---------------------------------------------------------------------------
__global__ __launch_bounds__(256) void attn_mean(
    const __bf16* __restrict__ Qh, const __bf16* __restrict__ Ql,
    const __bf16* __restrict__ Kh, const __bf16* __restrict__ Kl,
    const float* __restrict__ mask, const float* __restrict__ mrow,
    const float* __restrict__ lrow, float* __restrict__ meanout) {
  __shared__ __bf16 Ksh[64 * 72];
  __shared__ __bf16 Ksl[64 * 72];
  const int tid = threadIdx.x, lane = tid & 63, wv = tid >> 6;
  const int qd = lane >> 4, ln = lane & 15;
  const int qt = blockIdx.x, ks = blockIdx.y, b = blockIdx.z;
  const int q0w = qt * 64 + wv * 16;
  const int srow = tid >> 2, sseg = tid & 3;

  for (int kt2 = 0; kt2 < 4; kt2++) {
    const int kt = ks * 256 + kt2 * 64;
    float mk[4][4];
#pragma unroll
    for (int t = 0; t < 4; t++)
#pragma unroll
      for (int r = 0; r < 4; r++)
        mk[t][r] = mask[(size_t)(q0w + qd * 4 + r) * S_ + kt + t * 16 + ln];

    f4 macc[4];
#pragma unroll
    for (int t = 0; t < 4; t++)
#pragma unroll
      for (int r = 0; r < 4; r++) macc[t][r] = 0.f;

    for (int h = 0; h < H_; h++) {
      const int bh = b * H_ + h;
      const size_t qbase = ((size_t)bh * S_ + q0w + ln) * DK_;
      bfrag qh[2], qlf[2];
#pragma unroll
      for (int s = 0; s < 2; s++) {
        qh[s] = *(const bfrag*)&Qh[qbase + s * 32 + qd * 8];
        qlf[s] = *(const bfrag*)&Ql[qbase + s * 32 + qd * 8];
      }
      float m[4], invl[4];
#pragma unroll
      for (int r = 0; r < 4; r++) {
        m[r] = mrow[(size_t)bh * S_ + q0w + qd * 4 + r];
        invl[r] = 1.0f / lrow[(size_t)bh * S_ + q0w + qd * 4 + r];
      }
      const size_t kb = ((size_t)bh * S_ + kt + srow) * DK_ + sseg * 16;
      float4 h0 = *(const float4*)&Kh[kb], h1 = *(const float4*)&Kh[kb + 8];
      float4 l0 = *(const float4*)&Kl[kb], l1 = *(const float4*)&Kl[kb + 8];
      __syncthreads();
      *(float4*)&Ksh[srow * 72 + sseg * 16] = h0;
      *(float4*)&Ksh[srow * 72 + sseg * 16 + 8] = h1;
      *(float4*)&Ksl[srow * 72 + sseg * 16] = l0;
      *(float4*)&Ksl[srow * 72 + sseg * 16 + 8] = l1;
      __syncthreads();

#pragma unroll
      for (int t = 0; t < 4; t++) {
        f4 z;
#pragma unroll
        for (int r = 0; r < 4; r++) z[r] = 0.f;
#pragma unroll
        for (int s = 0; s < 2; s++) {
          bfrag kbh = *(bfrag*)&Ksh[(t * 16 + ln) * 72 + s * 32 + qd * 8];
          bfrag kbl = *(bfrag*)&Ksl[(t * 16 + ln) * 72 + s * 32 + qd * 8];
          z = MFMA16(qh[s], kbh, z);
          z = MFMA16(qh[s], kbl, z);
          z = MFMA16(qlf[s], kbh, z);
        }
#pragma unroll
        for (int r = 0; r < 4; r++) {
          const float zf = fmaf(z[r], SCALE, mk[t][r]);
          macc[t][r] += __expf(zf - m[r]) * invl[r];
        }
      }
    }
#pragma unroll
    for (int t = 0; t < 4; t++)
#pragma unroll
      for (int r = 0; r < 4; r++)
        meanout[((size_t)b * S_ + q0w + qd * 4 + r) * S_ + kt + t * 16 + ln] =
            macc[t][r] * 0.125f;
  }
}

// ---------------------------------------------------------------------------
extern "C" void kernel_launch(void* const* d_in, const int* in_sizes, int n_in,
                              void* d_out, int out_size, void* d_ws, size_t ws_size,
                              hipStream_t stream) {
  (void)in_sizes; (void)n_in; (void)out_size; (void)ws_size;
  const float* Zq = (const float*)d_in[0];
  const float* Zkv = (const float*)d_in[1];
  const float* mask = (const float*)d_in[2];
  const float* Wqkv = (const float*)d_in[3];
  const float* Wout = (const float*)d_in[4];

  float* out = (float*)d_out;               // [B,S,D]
  float* mean = out + (size_t)B_ * S_ * D_; // [B,S,S]

  char* w = (char*)d_ws;
  const size_t WSZ = 512 * 512 * sizeof(__bf16);   // 512KB
  const size_t QSZ = (size_t)B_ * H_ * S_ * DK_ * sizeof(__bf16);  // 8.4MB
  __bf16* WqTh = (__bf16*)w; w += WSZ;
  __bf16* WqTl = (__bf16*)w; w += WSZ;
  __bf16* WkTh = (__bf16*)w; w += WSZ;
  __bf16* WkTl = (__bf16*)w; w += WSZ;
  __bf16* WvTh = (__bf16*)w; w += WSZ;
  __bf16* WoTh = (__bf16*)w; w += WSZ;
  __bf16* Qh = (__bf16*)w; w += QSZ;
  __bf16* Ql = (__bf16*)w; w += QSZ;
  __bf16* Kh = (__bf16*)w; w += QSZ;
  __bf16* Kl = (__bf16*)w; w += QSZ;
  __bf16* VTh = (__bf16*)w; w += QSZ;
  __bf16* CTXb = (__bf16*)w; w += QSZ;
  float* MR = (float*)w; w += (size_t)B_ * H_ * S_ * sizeof(float);
  float* LR = (float*)w; w += (size_t)B_ * H_ * S_ * sizeof(float);

  wtr<<<1024, 256, 0, stream>>>(Wqkv, 1536, 0, WqTh, WqTl, 1);
  wtr<<<1024, 256, 0, stream>>>(Wqkv, 1536, 512, WkTh, WkTl, 1);
  wtr<<<1024, 256, 0, stream>>>(Wqkv, 1536, 1024, WvTh, nullptr, 0);
  wtr<<<1024, 256, 0, stream>>>(Wout, 512, 0, WoTh, nullptr, 0);

  gemm_mfma<true, false, true, 1><<<dim3(8, 128), 256, 0, stream>>>(
      Zq, WqTh, WqTl, nullptr, Qh, Ql);
  gemm_mfma<true, false, true, 1><<<dim3(8, 128), 256, 0, stream>>>(
      Zkv, WkTh, WkTl, nullptr, Kh, Kl);
  gemm_mfma<false, true, false, 2><<<dim3(128, 8), 256, 0, stream>>>(
      WvTh, Zkv, nullptr, nullptr, VTh, nullptr);

  attn_stats<<<dim3(32, 32), 256, 0, stream>>>(Qh, Ql, Kh, Kl, mask, MR, LR);
  attn_ctx<<<dim3(32, 32), 256, 0, stream>>>(Qh, Ql, Kh, Kl, VTh, mask, MR, LR, CTXb);
  attn_mean<<<dim3(32, 8, 4), 256, 0, stream>>>(Qh, Ql, Kh, Kl, mask, MR, LR, mean);

  gemm_mfma<false, false, false, 0><<<dim3(8, 128), 256, 0, stream>>>(
      CTXb, WoTh, nullptr, out, nullptr, nullptr);
}

// Round 3
// 485.564 us; speedup vs baseline: 5.7359x; 1.1055x over previous
//
#include <hip/hip_runtime.h>
#include <cstdint>

#define B_ 4
#define S_ 2048
#define D_ 512
#define H_ 8
#define DK_ 64
#define SCALE 0.125f
#define KSTR 84   // K/V LDS row stride in bf16 (frag reads & staging 2-way free)
#define PSTR 68   // Ps LDS row stride in bf16 (scalar stores conflict-free)

using bfrag = __attribute__((ext_vector_type(8))) __bf16;
using f4    = __attribute__((ext_vector_type(4))) float;

#define MFMA16(a, b, c) __builtin_amdgcn_mfma_f32_16x16x32_bf16(a, b, c, 0, 0, 0)

// ---------------------------------------------------------------------------
// Weight transpose + split: WT[n][k] = W[k][c0+n], hi/lo bf16.
// ---------------------------------------------------------------------------
__global__ __launch_bounds__(256) void wtr(const float* __restrict__ W, int ldw, int c0,
                                           __bf16* __restrict__ th, __bf16* __restrict__ tl,
                                           int do_lo) {
  int idx = blockIdx.x * 256 + threadIdx.x;  // 512*512
  int k = idx & 511, n = idx >> 9;
  float x = W[(size_t)k * ldw + c0 + n];
  __bf16 h = (__bf16)x;
  th[(size_t)n * 512 + k] = h;
  if (do_lo) tl[(size_t)n * 512 + k] = (__bf16)(x - (float)h);
}

// ---------------------------------------------------------------------------
// Split-bf16 MFMA GEMM (unchanged from round 2 — passed).
// ---------------------------------------------------------------------------
template <bool AF32, bool BF32, bool LO, int MODE>
__global__ __launch_bounds__(256) void gemm_mfma(
    const void* __restrict__ Ap, const void* __restrict__ Bp, const void* __restrict__ Blop,
    float* __restrict__ Cf, __bf16* __restrict__ Oh, __bf16* __restrict__ Ol) {
  __shared__ __bf16 Ash[64 * 40];
  __shared__ __bf16 Asl[64 * 40];
  __shared__ __bf16 Bsh[64 * 40];
  __shared__ __bf16 Bsl[64 * 40];

  const int tid = threadIdx.x;
  const int m0 = blockIdx.y * 64, n0 = blockIdx.x * 64;
  const int row = tid >> 2, seg = tid & 3;
  const int lane = tid & 63, wv = tid >> 6;
  const int wm = (wv & 1) * 32, wn = (wv >> 1) * 32;
  const int qd = lane >> 4, ln = lane & 15;

  f4 acc[2][2];
#pragma unroll
  for (int i = 0; i < 2; i++)
#pragma unroll
    for (int j = 0; j < 2; j++)
#pragma unroll
      for (int r = 0; r < 4; r++) acc[i][j][r] = 0.f;

  for (int kt = 0; kt < 512; kt += 32) {
    const size_t abase = (size_t)(m0 + row) * 512 + kt + seg * 8;
    const size_t bbase = (size_t)(n0 + row) * 512 + kt + seg * 8;
    float4 a0, a1, b0, b1, bl0;
    if constexpr (AF32) {
      const float* A = (const float*)Ap;
      a0 = *(const float4*)&A[abase];
      a1 = *(const float4*)&A[abase + 4];
    } else {
      const __bf16* A = (const __bf16*)Ap;
      a0 = *(const float4*)&A[abase];
    }
    if constexpr (BF32) {
      const float* Bm = (const float*)Bp;
      b0 = *(const float4*)&Bm[bbase];
      b1 = *(const float4*)&Bm[bbase + 4];
    } else {
      const __bf16* Bm = (const __bf16*)Bp;
      b0 = *(const float4*)&Bm[bbase];
      if constexpr (LO) {
        const __bf16* Bl = (const __bf16*)Blop;
        bl0 = *(const float4*)&Bl[bbase];
      }
    }
    __syncthreads();
    if constexpr (AF32) {
      float x[8] = {a0.x, a0.y, a0.z, a0.w, a1.x, a1.y, a1.z, a1.w};
      bfrag h, l;
#pragma unroll
      for (int j = 0; j < 8; j++) {
        h[j] = (__bf16)x[j];
        l[j] = (__bf16)(x[j] - (float)h[j]);
      }
      *(bfrag*)&Ash[row * 40 + seg * 8] = h;
      if constexpr (LO) *(bfrag*)&Asl[row * 40 + seg * 8] = l;
    } else {
      *(float4*)&Ash[row * 40 + seg * 8] = a0;
    }
    if constexpr (BF32) {
      float x[8] = {b0.x, b0.y, b0.z, b0.w, b1.x, b1.y, b1.z, b1.w};
      bfrag h;
#pragma unroll
      for (int j = 0; j < 8; j++) h[j] = (__bf16)x[j];
      *(bfrag*)&Bsh[row * 40 + seg * 8] = h;
    } else {
      *(float4*)&Bsh[row * 40 + seg * 8] = b0;
      if constexpr (LO) *(float4*)&Bsl[row * 40 + seg * 8] = bl0;
    }
    __syncthreads();

    bfrag ah[2], al[2], bh[2], bl[2];
#pragma unroll
    for (int mi = 0; mi < 2; mi++) {
      ah[mi] = *(bfrag*)&Ash[(wm + mi * 16 + ln) * 40 + qd * 8];
      if constexpr (LO) al[mi] = *(bfrag*)&Asl[(wm + mi * 16 + ln) * 40 + qd * 8];
    }
#pragma unroll
    for (int ni = 0; ni < 2; ni++) {
      bh[ni] = *(bfrag*)&Bsh[(wn + ni * 16 + ln) * 40 + qd * 8];
      if constexpr (LO) bl[ni] = *(bfrag*)&Bsl[(wn + ni * 16 + ln) * 40 + qd * 8];
    }
#pragma unroll
    for (int mi = 0; mi < 2; mi++)
#pragma unroll
      for (int ni = 0; ni < 2; ni++) {
        acc[mi][ni] = MFMA16(ah[mi], bh[ni], acc[mi][ni]);
        if constexpr (LO) {
          acc[mi][ni] = MFMA16(ah[mi], bl[ni], acc[mi][ni]);
          acc[mi][ni] = MFMA16(al[mi], bh[ni], acc[mi][ni]);
        }
      }
  }

#pragma unroll
  for (int mi = 0; mi < 2; mi++)
#pragma unroll
    for (int ni = 0; ni < 2; ni++)
#pragma unroll
      for (int r = 0; r < 4; r++) {
        const int mrow = m0 + wm + mi * 16 + qd * 4 + r;
        const int ncol = n0 + wn + ni * 16 + ln;
        const float c = acc[mi][ni][r];
        if constexpr (MODE == 0) {
          Cf[(size_t)mrow * 512 + ncol] = c;
        } else if constexpr (MODE == 1) {
          const int b = mrow >> 11, s = mrow & (S_ - 1);
          const int h = ncol >> 6, dk = ncol & 63;
          const size_t o = (((size_t)b * H_ + h) * S_ + s) * DK_ + dk;
          __bf16 hh = (__bf16)c;
          Oh[o] = hh;
          Ol[o] = (__bf16)(c - (float)hh);
        } else {  // MODE 2: V^T
          const int h = mrow >> 6, dk = mrow & 63;
          const int b = ncol >> 11, s = ncol & (S_ - 1);
          Oh[(((size_t)b * H_ + h) * DK_ + dk) * S_ + s] = (__bf16)c;
        }
      }
}

// ---------------------------------------------------------------------------
// Fused flash attention: online softmax + ctx in one pass.
// 4 waves x 32 q-rows = 128 q/block; grid (S/128, B*H).
// Writes bf16 ctx and final (m, l) per row for the mean kernel.
// ---------------------------------------------------------------------------
__global__ __launch_bounds__(256) void attn_fctx(
    const __bf16* __restrict__ Qh_, const __bf16* __restrict__ Ql_,
    const __bf16* __restrict__ Kh_, const __bf16* __restrict__ Kl_,
    const __bf16* __restrict__ VT, const float* __restrict__ mask,
    __bf16* __restrict__ CTXb, float* __restrict__ MR, float* __restrict__ LR) {
  __shared__ __bf16 Ksh[64 * KSTR];
  __shared__ __bf16 Ksl[64 * KSTR];
  __shared__ __bf16 Vs[64 * KSTR];
  __shared__ __bf16 Ps[128 * PSTR];
  const int tid = threadIdx.x, lane = tid & 63, wv = tid >> 6;
  const int qd = lane >> 4, ln = lane & 15;
  const int bh = blockIdx.y;
  const int q0w = blockIdx.x * 128 + wv * 32;
  const int srow = tid >> 2, sseg = tid & 3;

  bfrag qh[2][2], ql[2][2];
#pragma unroll
  for (int qi = 0; qi < 2; qi++)
#pragma unroll
    for (int s = 0; s < 2; s++) {
      const size_t qb = ((size_t)bh * S_ + q0w + qi * 16 + ln) * DK_ + s * 32 + qd * 8;
      qh[qi][s] = *(const bfrag*)&Qh_[qb];
      ql[qi][s] = *(const bfrag*)&Ql_[qb];
    }

  float m[2][4], l[2][4];
  f4 cacc[2][4];
#pragma unroll
  for (int qi = 0; qi < 2; qi++)
#pragma unroll
    for (int r = 0; r < 4; r++) {
      m[qi][r] = -3.0e38f;
      l[qi][r] = 0.f;
    }
#pragma unroll
  for (int qi = 0; qi < 2; qi++)
#pragma unroll
    for (int t = 0; t < 4; t++)
#pragma unroll
      for (int r = 0; r < 4; r++) cacc[qi][t][r] = 0.f;

  for (int kt = 0; kt < S_; kt += 64) {
    const size_t kb = ((size_t)bh * S_ + kt + srow) * DK_ + sseg * 16;
    const size_t vb = ((size_t)bh * DK_ + srow) * S_ + kt + sseg * 16;
    float4 h0 = *(const float4*)&Kh_[kb], h1 = *(const float4*)&Kh_[kb + 8];
    float4 l0 = *(const float4*)&Kl_[kb], l1 = *(const float4*)&Kl_[kb + 8];
    float4 v0 = *(const float4*)&VT[vb], v1 = *(const float4*)&VT[vb + 8];
    __syncthreads();
    *(float4*)&Ksh[srow * KSTR + sseg * 16] = h0;
    *(float4*)&Ksh[srow * KSTR + sseg * 16 + 8] = h1;
    *(float4*)&Ksl[srow * KSTR + sseg * 16] = l0;
    *(float4*)&Ksl[srow * KSTR + sseg * 16 + 8] = l1;
    *(float4*)&Vs[srow * KSTR + sseg * 16] = v0;
    *(float4*)&Vs[srow * KSTR + sseg * 16 + 8] = v1;
    __syncthreads();

    // QK^T (split-3)
    f4 z[2][4];
#pragma unroll
    for (int qi = 0; qi < 2; qi++)
#pragma unroll
      for (int t = 0; t < 4; t++)
#pragma unroll
        for (int r = 0; r < 4; r++) z[qi][t][r] = 0.f;
#pragma unroll
    for (int t = 0; t < 4; t++)
#pragma unroll
      for (int s = 0; s < 2; s++) {
        bfrag kbh = *(bfrag*)&Ksh[(t * 16 + ln) * KSTR + s * 32 + qd * 8];
        bfrag kbl = *(bfrag*)&Ksl[(t * 16 + ln) * KSTR + s * 32 + qd * 8];
#pragma unroll
        for (int qi = 0; qi < 2; qi++) {
          z[qi][t] = MFMA16(qh[qi][s], kbh, z[qi][t]);
          z[qi][t] = MFMA16(qh[qi][s], kbl, z[qi][t]);
          z[qi][t] = MFMA16(ql[qi][s], kbh, z[qi][t]);
        }
      }

    // online softmax: per-row tile max -> rescale -> store e to Ps
#pragma unroll
    for (int qi = 0; qi < 2; qi++) {
      float zf[4][4];
#pragma unroll
      for (int t = 0; t < 4; t++)
#pragma unroll
        for (int r = 0; r < 4; r++)
          zf[t][r] = fmaf(z[qi][t][r], SCALE,
                          mask[(size_t)(q0w + qi * 16 + qd * 4 + r) * S_ + kt + t * 16 + ln]);
#pragma unroll
      for (int r = 0; r < 4; r++) {
        float tm = fmaxf(fmaxf(zf[0][r], zf[1][r]), fmaxf(zf[2][r], zf[3][r]));
#pragma unroll
        for (int off = 1; off < 16; off <<= 1) tm = fmaxf(tm, __shfl_xor(tm, off, 64));
        const float nm = fmaxf(m[qi][r], tm);
        const float al = __expf(m[qi][r] - nm);
        m[qi][r] = nm;
        float e0 = __expf(zf[0][r] - nm), e1 = __expf(zf[1][r] - nm);
        float e2 = __expf(zf[2][r] - nm), e3 = __expf(zf[3][r] - nm);
        const int prow = (wv * 32 + qi * 16 + qd * 4 + r) * PSTR;
        Ps[prow + 0 * 16 + ln] = (__bf16)e0;
        Ps[prow + 1 * 16 + ln] = (__bf16)e1;
        Ps[prow + 2 * 16 + ln] = (__bf16)e2;
        Ps[prow + 3 * 16 + ln] = (__bf16)e3;
        l[qi][r] = l[qi][r] * al + (e0 + e1 + e2 + e3);  // lane-partial
#pragma unroll
        for (int t = 0; t < 4; t++) cacc[qi][t][r] *= al;
      }
    }

    // PV (Ps is wave-private: no barrier, lgkmcnt only)
    bfrag pa[2][2];
#pragma unroll
    for (int qi = 0; qi < 2; qi++)
#pragma unroll
      for (int s = 0; s < 2; s++)
        pa[qi][s] = *(bfrag*)&Ps[(wv * 32 + qi * 16 + ln) * PSTR + s * 32 + qd * 8];
#pragma unroll
    for (int t = 0; t < 4; t++)
#pragma unroll
      for (int s = 0; s < 2; s++) {
        bfrag vbf = *(bfrag*)&Vs[(t * 16 + ln) * KSTR + s * 32 + qd * 8];
#pragma unroll
        for (int qi = 0; qi < 2; qi++) cacc[qi][t] = MFMA16(pa[qi][s], vbf, cacc[qi][t]);
      }
  }

  // final row-sum reduction and output
#pragma unroll
  for (int qi = 0; qi < 2; qi++)
#pragma unroll
    for (int r = 0; r < 4; r++) {
      float ll = l[qi][r];
#pragma unroll
      for (int off = 1; off < 16; off <<= 1) ll += __shfl_xor(ll, off, 64);
      l[qi][r] = ll;
    }
  const int b = bh >> 3, h = bh & 7;
#pragma unroll
  for (int qi = 0; qi < 2; qi++)
#pragma unroll
    for (int r = 0; r < 4; r++) {
      const float inv = 1.0f / l[qi][r];
      const int s = q0w + qi * 16 + qd * 4 + r;
#pragma unroll
      for (int t = 0; t < 4; t++)
        CTXb[((size_t)b * S_ + s) * D_ + h * DK_ + t * 16 + ln] =
            (__bf16)(cacc[qi][t][r] * inv);
    }
  if (ln == 0) {
#pragma unroll
    for (int qi = 0; qi < 2; qi++)
#pragma unroll
      for (int r = 0; r < 4; r++) {
        MR[(size_t)bh * S_ + q0w + qi * 16 + qd * 4 + r] = m[qi][r];
        LR[(size_t)bh * S_ + q0w + qi * 16 + qd * 4 + r] = l[qi][r];
      }
  }
}

// ---------------------------------------------------------------------------
// Mean over heads of P, using final (m,l) from attn_fctx.
// 4 waves x 32 q-rows = 128 q/block; grid (S/128, 8 kv-slices, B); loops h.
// ---------------------------------------------------------------------------
__global__ __launch_bounds__(256) void attn_mean(
    const __bf16* __restrict__ Qh_, const __bf16* __restrict__ Ql_,
    const __bf16* __restrict__ Kh_, const __bf16* __restrict__ Kl_,
    const float* __restrict__ mask, const float* __restrict__ MR,
    const float* __restrict__ LR, float* __restrict__ meanout) {
  __shared__ __bf16 Ksh[64 * KSTR];
  __shared__ __bf16 Ksl[64 * KSTR];
  const int tid = threadIdx.x, lane = tid & 63, wv = tid >> 6;
  const int qd = lane >> 4, ln = lane & 15;
  const int qt = blockIdx.x, ks = blockIdx.y, b = blockIdx.z;
  const int q0w = qt * 128 + wv * 32;
  const int srow = tid >> 2, sseg = tid & 3;

  for (int kt2 = 0; kt2 < 4; kt2++) {
    const int kt = ks * 256 + kt2 * 64;
    float mk[2][4][4];
#pragma unroll
    for (int qi = 0; qi < 2; qi++)
#pragma unroll
      for (int t = 0; t < 4; t++)
#pragma unroll
        for (int r = 0; r < 4; r++)
          mk[qi][t][r] =
              mask[(size_t)(q0w + qi * 16 + qd * 4 + r) * S_ + kt + t * 16 + ln];

    f4 macc[2][4];
#pragma unroll
    for (int qi = 0; qi < 2; qi++)
#pragma unroll
      for (int t = 0; t < 4; t++)
#pragma unroll
        for (int r = 0; r < 4; r++) macc[qi][t][r] = 0.f;

    for (int h = 0; h < H_; h++) {
      const int bh = b * H_ + h;
      bfrag qh[2][2], qlf[2][2];
#pragma unroll
      for (int qi = 0; qi < 2; qi++)
#pragma unroll
        for (int s = 0; s < 2; s++) {
          const size_t qb = ((size_t)bh * S_ + q0w + qi * 16 + ln) * DK_ + s * 32 + qd * 8;
          qh[qi][s] = *(const bfrag*)&Qh_[qb];
          qlf[qi][s] = *(const bfrag*)&Ql_[qb];
        }
      float mm[2][4], li[2][4];
#pragma unroll
      for (int qi = 0; qi < 2; qi++)
#pragma unroll
        for (int r = 0; r < 4; r++) {
          mm[qi][r] = MR[(size_t)bh * S_ + q0w + qi * 16 + qd * 4 + r];
          li[qi][r] = 1.0f / LR[(size_t)bh * S_ + q0w + qi * 16 + qd * 4 + r];
        }

      const size_t kb = ((size_t)bh * S_ + kt + srow) * DK_ + sseg * 16;
      float4 h0 = *(const float4*)&Kh_[kb], h1 = *(const float4*)&Kh_[kb + 8];
      float4 l0 = *(const float4*)&Kl_[kb], l1 = *(const float4*)&Kl_[kb + 8];
      __syncthreads();
      *(float4*)&Ksh[srow * KSTR + sseg * 16] = h0;
      *(float4*)&Ksh[srow * KSTR + sseg * 16 + 8] = h1;
      *(float4*)&Ksl[srow * KSTR + sseg * 16] = l0;
      *(float4*)&Ksl[srow * KSTR + sseg * 16 + 8] = l1;
      __syncthreads();

      f4 z[2][4];
#pragma unroll
      for (int qi = 0; qi < 2; qi++)
#pragma unroll
        for (int t = 0; t < 4; t++)
#pragma unroll
          for (int r = 0; r < 4; r++) z[qi][t][r] = 0.f;
#pragma unroll
      for (int t = 0; t < 4; t++)
#pragma unroll
        for (int s = 0; s < 2; s++) {
          bfrag kbh = *(bfrag*)&Ksh[(t * 16 + ln) * KSTR + s * 32 + qd * 8];
          bfrag kbl = *(bfrag*)&Ksl[(t * 16 + ln) * KSTR + s * 32 + qd * 8];
#pragma unroll
          for (int qi = 0; qi < 2; qi++) {
            z[qi][t] = MFMA16(qh[qi][s], kbh, z[qi][t]);
            z[qi][t] = MFMA16(qh[qi][s], kbl, z[qi][t]);
            z[qi][t] = MFMA16(qlf[qi][s], kbh, z[qi][t]);
          }
        }
#pragma unroll
      for (int qi = 0; qi < 2; qi++)
#pragma unroll
        for (int t = 0; t < 4; t++)
#pragma unroll
          for (int r = 0; r < 4; r++)
            macc[qi][t][r] +=
                __expf(fmaf(z[qi][t][r], SCALE, mk[qi][t][r]) - mm[qi][r]) * li[qi][r];
    }

#pragma unroll
    for (int qi = 0; qi < 2; qi++)
#pragma unroll
      for (int t = 0; t < 4; t++)
#pragma unroll
        for (int r = 0; r < 4; r++)
          meanout[((size_t)b * S_ + q0w + qi * 16 + qd * 4 + r) * S_ + kt + t * 16 + ln] =
              macc[qi][t][r] * 0.125f;
  }
}

// ---------------------------------------------------------------------------
extern "C" void kernel_launch(void* const* d_in, const int* in_sizes, int n_in,
                              void* d_out, int out_size, void* d_ws, size_t ws_size,
                              hipStream_t stream) {
  (void)in_sizes; (void)n_in; (void)out_size; (void)ws_size;
  const float* Zq = (const float*)d_in[0];
  const float* Zkv = (const float*)d_in[1];
  const float* mask = (const float*)d_in[2];
  const float* Wqkv = (const float*)d_in[3];
  const float* Wout = (const float*)d_in[4];

  float* out = (float*)d_out;                // [B,S,D]
  float* mean = out + (size_t)B_ * S_ * D_;  // [B,S,S]

  char* w = (char*)d_ws;
  const size_t WSZ = 512 * 512 * sizeof(__bf16);
  const size_t QSZ = (size_t)B_ * H_ * S_ * DK_ * sizeof(__bf16);
  __bf16* WqTh = (__bf16*)w; w += WSZ;
  __bf16* WqTl = (__bf16*)w; w += WSZ;
  __bf16* WkTh = (__bf16*)w; w += WSZ;
  __bf16* WkTl = (__bf16*)w; w += WSZ;
  __bf16* WvTh = (__bf16*)w; w += WSZ;
  __bf16* WoTh = (__bf16*)w; w += WSZ;
  __bf16* Qh = (__bf16*)w; w += QSZ;
  __bf16* Ql = (__bf16*)w; w += QSZ;
  __bf16* Kh = (__bf16*)w; w += QSZ;
  __bf16* Kl = (__bf16*)w; w += QSZ;
  __bf16* VTh = (__bf16*)w; w += QSZ;
  __bf16* CTXb = (__bf16*)w; w += QSZ;
  float* MR = (float*)w; w += (size_t)B_ * H_ * S_ * sizeof(float);
  float* LR = (float*)w; w += (size_t)B_ * H_ * S_ * sizeof(float);

  wtr<<<1024, 256, 0, stream>>>(Wqkv, 1536, 0, WqTh, WqTl, 1);
  wtr<<<1024, 256, 0, stream>>>(Wqkv, 1536, 512, WkTh, WkTl, 1);
  wtr<<<1024, 256, 0, stream>>>(Wqkv, 1536, 1024, WvTh, nullptr, 0);
  wtr<<<1024, 256, 0, stream>>>(Wout, 512, 0, WoTh, nullptr, 0);

  gemm_mfma<true, false, true, 1><<<dim3(8, 128), 256, 0, stream>>>(
      Zq, WqTh, WqTl, nullptr, Qh, Ql);
  gemm_mfma<true, false, true, 1><<<dim3(8, 128), 256, 0, stream>>>(
      Zkv, WkTh, WkTl, nullptr, Kh, Kl);
  gemm_mfma<false, true, false, 2><<<dim3(128, 8), 256, 0, stream>>>(
      WvTh, Zkv, nullptr, nullptr, VTh, nullptr);

  attn_fctx<<<dim3(16, 32), 256, 0, stream>>>(Qh, Ql, Kh, Kl, VTh, mask, CTXb, MR, LR);
  attn_mean<<<dim3(16, 8, 4), 256, 0, stream>>>(Qh, Ql, Kh, Kl, mask, MR, LR, mean);

  gemm_mfma<false, false, false, 0><<<dim3(8, 128), 256, 0, stream>>>(
      CTXb, WoTh, nullptr, out, nullptr, nullptr);
}